// Round 4
// baseline (112.451 us; speedup 1.0000x reference)
//
#include <hip/hip_runtime.h>
#include <utility>

// Sparse Clebsch-Gordan tensor product, LMAX=3.
// out[b, mu3[k], c] += cg[k] * x[b, mu1[k], c] * y[b, mu2[k], c]
// B=1024, D_IN=16, D_OUT=156, C=128, K~1260 terms.
//
// R3 lesson: 2048 one-shot waves (2/SIMD) leave the kernel latency-bound at
// ~43 us (~2.7 TB/s) regardless of per-wave shape. R4: 4-way term-balanced
// row split -> 8192 waves (8/SIMD) of scalar-dword lanes. Reads duplicated
// ~2.5x (40 MB) but floor stays ~19.5 us and latency hiding quadruples.
// All indices remain compile-time (fold expressions); cg pre-gathered into
// row-sorted order in d_ws for consecutive s_load batches.

#define D_IN_ 16
#define D_OUT_ 156
#define C_ 128
#define KMAX_ 2048

struct CGRows {
    int n;
    int start[D_OUT_ + 1];  // row start offsets
    int k[KMAX_];           // original term index (for the gather)
    int m1[KMAX_];
    int m2[KMAX_];
};

constexpr CGRows build_rows() {
    int mu1[KMAX_] = {}, mu2[KMAX_] = {}, mu3[KMAX_] = {};
    int n = 0;
    const int off_in[4] = {0, 1, 4, 9};
    int off3 = 0;
    for (int l1 = 0; l1 <= 3; ++l1) {
        for (int l2 = 0; l2 <= 3; ++l2) {
            int lo = l1 > l2 ? l1 - l2 : l2 - l1;
            int hi = (l1 + l2) < 3 ? (l1 + l2) : 3;
            for (int l3 = lo; l3 <= hi; ++l3) {
                for (int m1 = 0; m1 < 2 * l1 + 1; ++m1) {
                    for (int m2 = 0; m2 < 2 * l2 + 1; ++m2) {
                        int a = m1 - l1, b = m2 - l2;
                        for (int m3 = 0; m3 < 2 * l3 + 1; ++m3) {
                            int c = m3 - l3;
                            int s = a + b; if (s < 0) s = -s;
                            int d = a - b; if (d < 0) d = -d;
                            int e = c < 0 ? -c : c;
                            if (s == e || d == e) {
                                mu1[n] = off_in[l1] + m1;
                                mu2[n] = off_in[l2] + m2;
                                mu3[n] = off3 + m3;
                                ++n;
                            }
                        }
                    }
                }
                off3 += 2 * l3 + 1;
            }
        }
    }
    CGRows r{};
    r.n = n;
    int cnt[D_OUT_] = {};
    for (int i = 0; i < n; ++i) cnt[mu3[i]]++;
    r.start[0] = 0;
    for (int j = 0; j < D_OUT_; ++j) r.start[j + 1] = r.start[j] + cnt[j];
    int pos[D_OUT_] = {};
    for (int j = 0; j < D_OUT_; ++j) pos[j] = r.start[j];
    for (int i = 0; i < n; ++i) {
        int j = mu3[i];
        int p = pos[j]++;
        r.k[p] = i;
        r.m1[p] = mu1[i];
        r.m2[p] = mu2[i];
    }
    return r;
}

constexpr CGRows CG = build_rows();
constexpr int K = CG.n;
static_assert(K <= KMAX_, "KMAX too small");

// Term-balanced quartile row boundaries.
constexpr int findq(int i) {
    int target = (CG.n * i) / 4;
    int j = 0;
    while (CG.start[j] < target) ++j;
    return j;
}
constexpr int QS0 = 0, QS1 = findq(1), QS2 = findq(2), QS3 = findq(3), QS4 = D_OUT_;

constexpr unsigned need1(int j0, int j1) {
    unsigned m = 0;
    for (int p = CG.start[j0]; p < CG.start[j1]; ++p) m |= 1u << CG.m1[p];
    return m;
}
constexpr unsigned need2(int j0, int j1) {
    unsigned m = 0;
    for (int p = CG.start[j0]; p < CG.start[j1]; ++p) m |= 1u << CG.m2[p];
    return m;
}

// Device copy of the gather indices (runtime-indexed -> lives in memory).
__device__ __constant__ CGRows dCG = build_rows();

__global__ void gather_cg(const float* __restrict__ cg, float* __restrict__ cgs) {
    int i = blockIdx.x * 256 + threadIdx.x;
    if (i < K) cgs[i] = cg[dCG.k[i]];
}

template <unsigned M, int I>
__device__ __forceinline__ void load1(float (&v)[D_IN_], const float* __restrict__ base) {
    if constexpr ((M >> I) & 1u) v[I] = base[I * C_];
    else v[I] = 0.0f;
}

template <unsigned M, int... Is>
__device__ __forceinline__ void load_masked(float (&v)[D_IN_], const float* __restrict__ base,
                                            std::integer_sequence<int, Is...>) {
    (load1<M, Is>(v, base), ...);
}

template <int Base, int... Ts>
__device__ __forceinline__ float row_sum(const float* __restrict__ cgs,
                                         const float (&xv)[D_IN_],
                                         const float (&yv)[D_IN_],
                                         std::integer_sequence<int, Ts...>) {
    float s = 0.0f;
    ((s = fmaf(cgs[Base + Ts], xv[CG.m1[Base + Ts]] * yv[CG.m2[Base + Ts]], s)), ...);
    return s;
}

template <int J>
__device__ __forceinline__ void store_row(float* __restrict__ ob, const float* __restrict__ cgs,
                                          const float (&xv)[D_IN_], const float (&yv)[D_IN_]) {
    constexpr int base = CG.start[J];
    constexpr int nt = CG.start[J + 1] - CG.start[J];
    ob[J * C_] = row_sum<base>(cgs, xv, yv, std::make_integer_sequence<int, nt>{});
}

template <int J0, int... Js>
__device__ __forceinline__ void rows_range(float* __restrict__ ob, const float* __restrict__ cgs,
                                           const float (&xv)[D_IN_], const float (&yv)[D_IN_],
                                           std::integer_sequence<int, Js...>) {
    (store_row<J0 + Js>(ob, cgs, xv, yv), ...);
}

template <int J0, int J1>
__device__ __forceinline__ void do_range(const float* __restrict__ xb,
                                         const float* __restrict__ yb,
                                         float* __restrict__ ob,
                                         const float* __restrict__ cgs) {
    constexpr unsigned M1 = need1(J0, J1), M2 = need2(J0, J1);
    float xv[D_IN_], yv[D_IN_];
    load_masked<M1>(xv, xb, std::make_integer_sequence<int, D_IN_>{});
    load_masked<M2>(yv, yb, std::make_integer_sequence<int, D_IN_>{});
    rows_range<J0>(ob, cgs, xv, yv, std::make_integer_sequence<int, J1 - J0>{});
}

__global__ __launch_bounds__(256, 4) void tp_cg_kernel(
    const float* __restrict__ x, const float* __restrict__ y,
    const float* __restrict__ cgs, float* __restrict__ out) {
    const int tid = (int)threadIdx.x;
    const int c = tid & (C_ - 1);
    const int b = (int)(blockIdx.x >> 1);
    const int q = (int)(((blockIdx.x & 1) << 1) | (tid >> 7));  // wave-uniform

    const float* xb = x + (size_t)b * (D_IN_ * C_) + c;
    const float* yb = y + (size_t)b * (D_IN_ * C_) + c;
    float* ob = out + (size_t)b * (D_OUT_ * C_) + c;

    if (q == 0)      do_range<QS0, QS1>(xb, yb, ob, cgs);
    else if (q == 1) do_range<QS1, QS2>(xb, yb, ob, cgs);
    else if (q == 2) do_range<QS2, QS3>(xb, yb, ob, cgs);
    else             do_range<QS3, QS4>(xb, yb, ob, cgs);
}

extern "C" void kernel_launch(void* const* d_in, const int* in_sizes, int n_in,
                              void* d_out, int out_size, void* d_ws, size_t ws_size,
                              hipStream_t stream) {
    const float* x  = (const float*)d_in[0];
    const float* y  = (const float*)d_in[1];
    const float* cg = (const float*)d_in[2];
    float* out = (float*)d_out;
    float* cgs = (float*)d_ws;  // K floats of row-sorted coefficients

    const int B = in_sizes[0] / (D_IN_ * C_);

    gather_cg<<<(K + 255) / 256, 256, 0, stream>>>(cg, cgs);

    // block = 128 c-lanes x 2 quarters; grid = B x 2 quarter-pairs
    tp_cg_kernel<<<B * 2, 256, 0, stream>>>(x, y, cgs, out);
}